// Round 1
// baseline (2860.772 us; speedup 1.0000x reference)
//
#include <hip/hip_runtime.h>
#include <hip/hip_bf16.h>

#define D 128
#define WPAD 136   // padded K-stride for transposed W in LDS (breaks bank conflicts)

typedef __attribute__((ext_vector_type(8))) short short8;
typedef __attribute__((ext_vector_type(8))) __bf16 bf16x8;
typedef __attribute__((ext_vector_type(4))) float float4_t;

__device__ __forceinline__ short f2bf(float f) {
    __hip_bfloat16 b = __float2bfloat16(f);   // RTNE
    return __builtin_bit_cast(short, b);
}

__device__ __forceinline__ short8 load_frag8(const float* p) {
    const float4_t* q = reinterpret_cast<const float4_t*>(p);
    float4_t u = q[0], v = q[1];
    short8 r;
    r[0] = f2bf(u[0]); r[1] = f2bf(u[1]); r[2] = f2bf(u[2]); r[3] = f2bf(u[3]);
    r[4] = f2bf(v[0]); r[5] = f2bf(v[1]); r[6] = f2bf(v[2]); r[7] = f2bf(v[3]);
    return r;
}

__device__ __forceinline__ float4_t mfma_bf16(short8 a, short8 b, float4_t c) {
    return __builtin_amdgcn_mfma_f32_16x16x32_bf16(
        __builtin_bit_cast(bf16x8, a), __builtin_bit_cast(bf16x8, b), c, 0, 0, 0);
}

// ---------------------------------------------------------------------------
// SpMM scatter: agg[row] += val * x[col].  32 lanes per edge, float4 per lane,
// contiguous atomicAdds (no same-address contention within an edge).
// ---------------------------------------------------------------------------
__global__ __launch_bounds__(256) void scatter_kernel(
    const float* __restrict__ x, const int* __restrict__ erow,
    const int* __restrict__ ecol, const float* __restrict__ eval,
    float* __restrict__ agg, int E)
{
    long long gid = (long long)blockIdx.x * 256 + threadIdx.x;
    int e    = (int)(gid >> 5);
    int lane = (int)(gid & 31);
    if (e >= E) return;
    int   r = erow[e];
    int   c = ecol[e];
    float v = eval[e];
    float4_t xv = reinterpret_cast<const float4_t*>(x + (size_t)c * D)[lane];
    float* dst = agg + (size_t)r * D + lane * 4;
    atomicAdd(dst + 0, v * xv[0]);
    atomicAdd(dst + 1, v * xv[1]);
    atomicAdd(dst + 2, v * xv[2]);
    atomicAdd(dst + 3, v * xv[3]);
}

// ---------------------------------------------------------------------------
// Dual GEMM + bias + ReLU + concat epilogue.
// out[:, :128] = relu(x @ Wl + bl), out[:, 128:] = relu(agg @ Wn + bn)
// Block = 256 threads = 4 waves; each wave does 32 rows x 128 cols, both GEMMs.
// W (stored [K][N] in global) is transposed to LDS as Wt[n][k], bf16, stride 136.
// MFMA 16x16x32 bf16: A[m=lane&15][k=quad*8+j], B[n=lane&15][k=quad*8+j],
//                     D: col=lane&15, row=quad*4+reg.
// ---------------------------------------------------------------------------
__global__ __launch_bounds__(256) void dual_gemm_kernel(
    const float* __restrict__ x, const float* __restrict__ agg,
    const float* __restrict__ Wl, const float* __restrict__ bl,
    const float* __restrict__ Wn, const float* __restrict__ bn,
    float* __restrict__ out, int N)
{
    __shared__ short lWl[D * WPAD];
    __shared__ short lWn[D * WPAD];
    for (int i = threadIdx.x; i < D * D; i += 256) {
        int k = i >> 7, n = i & (D - 1);
        lWl[n * WPAD + k] = f2bf(Wl[i]);   // coalesced global read, LDS transpose
        lWn[n * WPAD + k] = f2bf(Wn[i]);
    }
    __syncthreads();

    int wave = threadIdx.x >> 6;
    int lane = threadIdx.x & 63;
    int quad = lane >> 4;
    int l16  = lane & 15;
    int rbase = blockIdx.x * 128 + wave * 32;

    // A-fragments for 2 row-groups x 4 k-tiles, both matrices (x and agg)
    short8 ax[2][4], ag[2][4];
    for (int m = 0; m < 2; ++m) {
        int row  = rbase + m * 16 + l16;
        int rowc = row < N ? row : N - 1;           // clamp: loads stay in-bounds
        const float* xp = x   + (size_t)rowc * D + quad * 8;
        const float* gp = agg + (size_t)rowc * D + quad * 8;
        for (int t = 0; t < 4; ++t) {
            ax[m][t] = load_frag8(xp + t * 32);
            ag[m][t] = load_frag8(gp + t * 32);
        }
    }

    for (int nt = 0; nt < 8; ++nt) {
        int colc = nt * 16 + l16;
        float4_t accl[2], accn[2];
        accl[0] = accl[1] = accn[0] = accn[1] = (float4_t){0.f, 0.f, 0.f, 0.f};
        const short* bpl = lWl + colc * WPAD + quad * 8;
        const short* bpn = lWn + colc * WPAD + quad * 8;
        for (int t = 0; t < 4; ++t) {
            short8 bfl = *reinterpret_cast<const short8*>(bpl + t * 32);
            short8 bfn = *reinterpret_cast<const short8*>(bpn + t * 32);
            accl[0] = mfma_bf16(ax[0][t], bfl, accl[0]);
            accl[1] = mfma_bf16(ax[1][t], bfl, accl[1]);
            accn[0] = mfma_bf16(ag[0][t], bfn, accn[0]);
            accn[1] = mfma_bf16(ag[1][t], bfn, accn[1]);
        }
        float bLc = bl[colc];
        float bNc = bn[colc];
        for (int m = 0; m < 2; ++m) {
            int row0 = rbase + m * 16 + quad * 4;
            for (int i = 0; i < 4; ++i) {
                int rr = row0 + i;
                if (rr < N) {
                    float lv = accl[m][i] + bLc;
                    float nv = accn[m][i] + bNc;
                    out[(size_t)rr * 256 + colc]       = lv > 0.f ? lv : 0.f;
                    out[(size_t)rr * 256 + D + colc]   = nv > 0.f ? nv : 0.f;
                }
            }
        }
    }
}

extern "C" void kernel_launch(void* const* d_in, const int* in_sizes, int n_in,
                              void* d_out, int out_size, void* d_ws, size_t ws_size,
                              hipStream_t stream) {
    const float* x    = (const float*)d_in[0];
    const int*   erow = (const int*)  d_in[1];
    const int*   ecol = (const int*)  d_in[2];
    const float* eval = (const float*)d_in[3];
    const float* Wl   = (const float*)d_in[4];
    const float* bl   = (const float*)d_in[5];
    const float* Wn   = (const float*)d_in[6];
    const float* bn   = (const float*)d_in[7];
    float*       out  = (float*)d_out;

    int N = in_sizes[0] / D;
    int E = in_sizes[1];

    float* agg = (float*)d_ws;   // N*D fp32 = 51.2 MB scratch

    hipMemsetAsync(agg, 0, (size_t)N * D * sizeof(float), stream);

    long long sthreads = (long long)E * 32;
    int sblocks = (int)((sthreads + 255) / 256);
    scatter_kernel<<<sblocks, 256, 0, stream>>>(x, erow, ecol, eval, agg, E);

    int gblocks = (N + 127) / 128;
    dual_gemm_kernel<<<gblocks, 256, 0, stream>>>(x, agg, Wl, bl, Wn, bn, out, N);
}

// Round 2
// 517.644 us; speedup vs baseline: 5.5265x; 5.5265x over previous
//
#include <hip/hip_runtime.h>
#include <hip/hip_bf16.h>

#define D 128
#define WPAD 136   // padded K-stride for transposed W in LDS

typedef __attribute__((ext_vector_type(8))) short short8;
typedef __attribute__((ext_vector_type(8))) __bf16 bf16x8;
typedef __attribute__((ext_vector_type(4))) float float4_t;

__device__ __forceinline__ short f2bf(float f) {
    __hip_bfloat16 b = __float2bfloat16(f);   // RTNE
    return __builtin_bit_cast(short, b);
}

__device__ __forceinline__ short8 load_frag8(const float* p) {
    const float4_t* q = reinterpret_cast<const float4_t*>(p);
    float4_t u = q[0], v = q[1];
    short8 r;
    r[0] = f2bf(u[0]); r[1] = f2bf(u[1]); r[2] = f2bf(u[2]); r[3] = f2bf(u[3]);
    r[4] = f2bf(v[0]); r[5] = f2bf(v[1]); r[6] = f2bf(v[2]); r[7] = f2bf(v[3]);
    return r;
}

__device__ __forceinline__ float4_t mfma_bf16(short8 a, short8 b, float4_t c) {
    return __builtin_amdgcn_mfma_f32_16x16x32_bf16(
        __builtin_bit_cast(bf16x8, a), __builtin_bit_cast(bf16x8, b), c, 0, 0, 0);
}

// ---------------------------------------------------------------------------
// CSR build: histogram -> scan -> reorder
// ---------------------------------------------------------------------------
__global__ __launch_bounds__(256) void hist_kernel(
    const int* __restrict__ erow, int* __restrict__ count, int E)
{
    int e = blockIdx.x * 256 + threadIdx.x;
    if (e < E) atomicAdd(&count[erow[e]], 1);
}

// per-block inclusive scan of 256 counts; emits per-element inclusive + block sum
__global__ __launch_bounds__(256) void scan1_kernel(
    const int* __restrict__ count, int* __restrict__ tmp,
    int* __restrict__ bsum, int N)
{
    __shared__ int s[256];
    int tid = threadIdx.x;
    int i = blockIdx.x * 256 + tid;
    int v = (i < N) ? count[i] : 0;
    s[tid] = v;
    __syncthreads();
    for (int off = 1; off < 256; off <<= 1) {
        int t = (tid >= off) ? s[tid - off] : 0;
        __syncthreads();
        s[tid] += t;
        __syncthreads();
    }
    if (i < N) tmp[i] = s[tid];
    if (tid == 255) bsum[blockIdx.x] = s[255];
}

// single-block exclusive scan of block sums (nb <= 1024)
__global__ __launch_bounds__(1024) void scan2_kernel(int* __restrict__ bsum, int nb)
{
    __shared__ int s[1024];
    int tid = threadIdx.x;
    int v = (tid < nb) ? bsum[tid] : 0;
    s[tid] = v;
    __syncthreads();
    for (int off = 1; off < 1024; off <<= 1) {
        int t = (tid >= off) ? s[tid - off] : 0;
        __syncthreads();
        s[tid] += t;
        __syncthreads();
    }
    if (tid < nb) bsum[tid] = s[tid] - v;   // exclusive
}

__global__ __launch_bounds__(256) void scan3_kernel(
    const int* __restrict__ count, const int* __restrict__ tmp,
    const int* __restrict__ bsum, int* __restrict__ start,
    int* __restrict__ cursor, int N, int E)
{
    int i = blockIdx.x * 256 + threadIdx.x;
    if (i < N) {
        int st = tmp[i] - count[i] + bsum[blockIdx.x];
        start[i] = st;
        cursor[i] = st;
    }
    if (i == 0) start[N] = E;
}

__global__ __launch_bounds__(256) void reorder_kernel(
    const int* __restrict__ erow, const int* __restrict__ ecol,
    const float* __restrict__ eval, int* __restrict__ cursor,
    int2* __restrict__ pairs, int E)
{
    int e = blockIdx.x * 256 + threadIdx.x;
    if (e >= E) return;
    int r = erow[e];
    int pos = atomicAdd(&cursor[r], 1);
    pairs[pos] = make_int2(ecol[e], __float_as_int(eval[e]));
}

// ---------------------------------------------------------------------------
// Pull-based segment sum: one wave per node, lane owns float2 of the 128-dim.
// agg[n] = sum_{j in row n} val_j * x[col_j]. No atomics, no memset needed.
// ---------------------------------------------------------------------------
__global__ __launch_bounds__(256) void gather_kernel(
    const float* __restrict__ x, const int* __restrict__ start,
    const int2* __restrict__ pairs, float* __restrict__ agg, int N)
{
    int node = blockIdx.x * 4 + (threadIdx.x >> 6);
    if (node >= N) return;
    int lane = threadIdx.x & 63;
    int s = start[node];
    int e = start[node + 1];
    const float2* xv = reinterpret_cast<const float2*>(x);
    float2 acc = make_float2(0.f, 0.f);
    int j = s;
    for (; j + 1 < e; j += 2) {           // 2-edge unroll for ILP
        int2 p0 = pairs[j];
        int2 p1 = pairs[j + 1];
        float2 t0 = xv[(size_t)p0.x * 64 + lane];
        float2 t1 = xv[(size_t)p1.x * 64 + lane];
        float v0 = __int_as_float(p0.y);
        float v1 = __int_as_float(p1.y);
        acc.x += v0 * t0.x; acc.y += v0 * t0.y;
        acc.x += v1 * t1.x; acc.y += v1 * t1.y;
    }
    if (j < e) {
        int2 p0 = pairs[j];
        float2 t0 = xv[(size_t)p0.x * 64 + lane];
        float v0 = __int_as_float(p0.y);
        acc.x += v0 * t0.x; acc.y += v0 * t0.y;
    }
    reinterpret_cast<float2*>(agg)[(size_t)node * 64 + lane] = acc;
}

// ---------------------------------------------------------------------------
// Fallback scatter (used only if ws_size too small for CSR path)
// ---------------------------------------------------------------------------
__global__ __launch_bounds__(256) void scatter_kernel(
    const float* __restrict__ x, const int* __restrict__ erow,
    const int* __restrict__ ecol, const float* __restrict__ eval,
    float* __restrict__ agg, int E)
{
    long long gid = (long long)blockIdx.x * 256 + threadIdx.x;
    int e    = (int)(gid >> 5);
    int lane = (int)(gid & 31);
    if (e >= E) return;
    int   r = erow[e];
    int   c = ecol[e];
    float v = eval[e];
    float4_t xvv = reinterpret_cast<const float4_t*>(x + (size_t)c * D)[lane];
    float* dst = agg + (size_t)r * D + lane * 4;
    atomicAdd(dst + 0, v * xvv[0]);
    atomicAdd(dst + 1, v * xvv[1]);
    atomicAdd(dst + 2, v * xvv[2]);
    atomicAdd(dst + 3, v * xvv[3]);
}

// ---------------------------------------------------------------------------
// Dual GEMM + bias + ReLU + concat epilogue (unchanged from round 1).
// ---------------------------------------------------------------------------
__global__ __launch_bounds__(256) void dual_gemm_kernel(
    const float* __restrict__ x, const float* __restrict__ agg,
    const float* __restrict__ Wl, const float* __restrict__ bl,
    const float* __restrict__ Wn, const float* __restrict__ bn,
    float* __restrict__ out, int N)
{
    __shared__ short lWl[D * WPAD];
    __shared__ short lWn[D * WPAD];
    for (int i = threadIdx.x; i < D * D; i += 256) {
        int k = i >> 7, n = i & (D - 1);
        lWl[n * WPAD + k] = f2bf(Wl[i]);
        lWn[n * WPAD + k] = f2bf(Wn[i]);
    }
    __syncthreads();

    int wave = threadIdx.x >> 6;
    int lane = threadIdx.x & 63;
    int quad = lane >> 4;
    int l16  = lane & 15;
    int rbase = blockIdx.x * 128 + wave * 32;

    short8 ax[2][4], ag[2][4];
    for (int m = 0; m < 2; ++m) {
        int row  = rbase + m * 16 + l16;
        int rowc = row < N ? row : N - 1;
        const float* xp = x   + (size_t)rowc * D + quad * 8;
        const float* gp = agg + (size_t)rowc * D + quad * 8;
        for (int t = 0; t < 4; ++t) {
            ax[m][t] = load_frag8(xp + t * 32);
            ag[m][t] = load_frag8(gp + t * 32);
        }
    }

    for (int nt = 0; nt < 8; ++nt) {
        int colc = nt * 16 + l16;
        float4_t accl[2], accn[2];
        accl[0] = accl[1] = accn[0] = accn[1] = (float4_t){0.f, 0.f, 0.f, 0.f};
        const short* bpl = lWl + colc * WPAD + quad * 8;
        const short* bpn = lWn + colc * WPAD + quad * 8;
        for (int t = 0; t < 4; ++t) {
            short8 bfl = *reinterpret_cast<const short8*>(bpl + t * 32);
            short8 bfn = *reinterpret_cast<const short8*>(bpn + t * 32);
            accl[0] = mfma_bf16(ax[0][t], bfl, accl[0]);
            accl[1] = mfma_bf16(ax[1][t], bfl, accl[1]);
            accn[0] = mfma_bf16(ag[0][t], bfn, accn[0]);
            accn[1] = mfma_bf16(ag[1][t], bfn, accn[1]);
        }
        float bLc = bl[colc];
        float bNc = bn[colc];
        for (int m = 0; m < 2; ++m) {
            int row0 = rbase + m * 16 + quad * 4;
            for (int i = 0; i < 4; ++i) {
                int rr = row0 + i;
                if (rr < N) {
                    float lv = accl[m][i] + bLc;
                    float nv = accn[m][i] + bNc;
                    out[(size_t)rr * 256 + colc]       = lv > 0.f ? lv : 0.f;
                    out[(size_t)rr * 256 + D + colc]   = nv > 0.f ? nv : 0.f;
                }
            }
        }
    }
}

extern "C" void kernel_launch(void* const* d_in, const int* in_sizes, int n_in,
                              void* d_out, int out_size, void* d_ws, size_t ws_size,
                              hipStream_t stream) {
    const float* x    = (const float*)d_in[0];
    const int*   erow = (const int*)  d_in[1];
    const int*   ecol = (const int*)  d_in[2];
    const float* eval = (const float*)d_in[3];
    const float* Wl   = (const float*)d_in[4];
    const float* bl   = (const float*)d_in[5];
    const float* Wn   = (const float*)d_in[6];
    const float* bn   = (const float*)d_in[7];
    float*       out  = (float*)d_out;

    int N = in_sizes[0] / D;
    int E = in_sizes[1];

    char* ws = (char*)d_ws;
    size_t off_agg    = 0;
    size_t off_pairs  = off_agg + (size_t)N * D * sizeof(float);          // 8B-aligned
    size_t off_count  = off_pairs + (size_t)E * sizeof(int2);
    size_t off_tmp    = off_count + (size_t)N * sizeof(int);
    size_t off_start  = off_tmp + (size_t)N * sizeof(int);
    size_t off_cursor = off_start + (size_t)(N + 2) * sizeof(int);
    size_t off_bsum   = off_cursor + (size_t)N * sizeof(int);
    size_t needed     = off_bsum + 1024 * sizeof(int);

    float* agg = (float*)(ws + off_agg);
    int nblocksN = (N + 255) / 256;
    int nblocksE = (E + 255) / 256;

    if (ws_size >= needed && nblocksN <= 1024) {
        int2* pairs  = (int2*)(ws + off_pairs);
        int*  count  = (int*)(ws + off_count);
        int*  tmp    = (int*)(ws + off_tmp);
        int*  start  = (int*)(ws + off_start);
        int*  cursor = (int*)(ws + off_cursor);
        int*  bsum   = (int*)(ws + off_bsum);

        hipMemsetAsync(count, 0, (size_t)N * sizeof(int), stream);
        hist_kernel<<<nblocksE, 256, 0, stream>>>(erow, count, E);
        scan1_kernel<<<nblocksN, 256, 0, stream>>>(count, tmp, bsum, N);
        scan2_kernel<<<1, 1024, 0, stream>>>(bsum, nblocksN);
        scan3_kernel<<<nblocksN, 256, 0, stream>>>(count, tmp, bsum, start, cursor, N, E);
        reorder_kernel<<<nblocksE, 256, 0, stream>>>(erow, ecol, eval, cursor, pairs, E);
        gather_kernel<<<(N + 3) / 4, 256, 0, stream>>>(x, start, pairs, agg, N);
    } else {
        hipMemsetAsync(agg, 0, (size_t)N * D * sizeof(float), stream);
        long long sthreads = (long long)E * 32;
        int sblocks = (int)((sthreads + 255) / 256);
        scatter_kernel<<<sblocks, 256, 0, stream>>>(x, erow, ecol, eval, agg, E);
    }

    int gblocks = (N + 127) / 128;
    dual_gemm_kernel<<<gblocks, 256, 0, stream>>>(x, agg, Wl, bl, Wn, bn, out, N);
}

// Round 3
// 458.565 us; speedup vs baseline: 6.2385x; 1.1288x over previous
//
#include <hip/hip_runtime.h>
#include <hip/hip_bf16.h>

#define D 128
#define WPAD 136   // padded K-stride for transposed W in LDS

typedef __attribute__((ext_vector_type(8))) short short8;
typedef __attribute__((ext_vector_type(8))) __bf16 bf16x8;
typedef __attribute__((ext_vector_type(4))) float float4_t;

__device__ __forceinline__ short f2bf(float f) {
    __hip_bfloat16 b = __float2bfloat16(f);   // RTNE
    return __builtin_bit_cast(short, b);
}

__device__ __forceinline__ short8 load_frag8(const float* p) {
    const float4_t* q = reinterpret_cast<const float4_t*>(p);
    float4_t u = q[0], v = q[1];
    short8 r;
    r[0] = f2bf(u[0]); r[1] = f2bf(u[1]); r[2] = f2bf(u[2]); r[3] = f2bf(u[3]);
    r[4] = f2bf(v[0]); r[5] = f2bf(v[1]); r[6] = f2bf(v[2]); r[7] = f2bf(v[3]);
    return r;
}

__device__ __forceinline__ float4_t mfma_bf16(short8 a, short8 b, float4_t c) {
    return __builtin_amdgcn_mfma_f32_16x16x32_bf16(
        __builtin_bit_cast(bf16x8, a), __builtin_bit_cast(bf16x8, b), c, 0, 0, 0);
}

__device__ __forceinline__ float bf_lo(unsigned u) { return __uint_as_float(u << 16); }
__device__ __forceinline__ float bf_hi(unsigned u) { return __uint_as_float(u & 0xFFFF0000u); }

// ---------------------------------------------------------------------------
// CSR build: histogram -> scan -> reorder
// ---------------------------------------------------------------------------
__global__ __launch_bounds__(256) void hist_kernel(
    const int* __restrict__ erow, int* __restrict__ count, int E)
{
    int e = blockIdx.x * 256 + threadIdx.x;
    if (e < E) atomicAdd(&count[erow[e]], 1);
}

__global__ __launch_bounds__(256) void scan1_kernel(
    const int* __restrict__ count, int* __restrict__ tmp,
    int* __restrict__ bsum, int N)
{
    __shared__ int s[256];
    int tid = threadIdx.x;
    int i = blockIdx.x * 256 + tid;
    int v = (i < N) ? count[i] : 0;
    s[tid] = v;
    __syncthreads();
    for (int off = 1; off < 256; off <<= 1) {
        int t = (tid >= off) ? s[tid - off] : 0;
        __syncthreads();
        s[tid] += t;
        __syncthreads();
    }
    if (i < N) tmp[i] = s[tid];
    if (tid == 255) bsum[blockIdx.x] = s[255];
}

__global__ __launch_bounds__(1024) void scan2_kernel(int* __restrict__ bsum, int nb)
{
    __shared__ int s[1024];
    int tid = threadIdx.x;
    int v = (tid < nb) ? bsum[tid] : 0;
    s[tid] = v;
    __syncthreads();
    for (int off = 1; off < 1024; off <<= 1) {
        int t = (tid >= off) ? s[tid - off] : 0;
        __syncthreads();
        s[tid] += t;
        __syncthreads();
    }
    if (tid < nb) bsum[tid] = s[tid] - v;   // exclusive
}

__global__ __launch_bounds__(256) void scan3_kernel(
    const int* __restrict__ count, const int* __restrict__ tmp,
    const int* __restrict__ bsum, int* __restrict__ start,
    int* __restrict__ cursor, int N, int E)
{
    int i = blockIdx.x * 256 + threadIdx.x;
    if (i < N) {
        int st = tmp[i] - count[i] + bsum[blockIdx.x];
        start[i] = st;
        cursor[i] = st;
    }
    if (i == 0) start[N] = E;
}

__global__ __launch_bounds__(256) void reorder_kernel(
    const int* __restrict__ erow, const int* __restrict__ ecol,
    const float* __restrict__ eval, int* __restrict__ cursor,
    int2* __restrict__ pairs, int E)
{
    int e = blockIdx.x * 256 + threadIdx.x;
    if (e >= E) return;
    int r = erow[e];
    int pos = atomicAdd(&cursor[r], 1);
    pairs[pos] = make_int2(ecol[e], __float_as_int(eval[e]));
}

// ---------------------------------------------------------------------------
// Fused GEMM: out[:, :128] = relu(x@Wl + bl)  (fp32)
//             y            = x@Wn             (bf16, bias deferred to gather)
// Both GEMMs share the same A fragments (x rows).
// ---------------------------------------------------------------------------
__global__ __launch_bounds__(256) void gemm_kernel(
    const float* __restrict__ x,
    const float* __restrict__ Wl, const float* __restrict__ bl,
    const float* __restrict__ Wn,
    float* __restrict__ out, unsigned short* __restrict__ y, int N)
{
    __shared__ short lWl[D * WPAD];
    __shared__ short lWn[D * WPAD];
    for (int i = threadIdx.x; i < D * D; i += 256) {
        int k = i >> 7, n = i & (D - 1);
        lWl[n * WPAD + k] = f2bf(Wl[i]);   // coalesced read, transposed LDS store
        lWn[n * WPAD + k] = f2bf(Wn[i]);
    }
    __syncthreads();

    int wave = threadIdx.x >> 6;
    int lane = threadIdx.x & 63;
    int quad = lane >> 4;
    int l16  = lane & 15;
    int rbase = blockIdx.x * 128 + wave * 32;

    short8 ax[2][4];
    for (int m = 0; m < 2; ++m) {
        int row  = rbase + m * 16 + l16;
        int rowc = row < N ? row : N - 1;
        const float* xp = x + (size_t)rowc * D + quad * 8;
        for (int t = 0; t < 4; ++t) ax[m][t] = load_frag8(xp + t * 32);
    }

    for (int nt = 0; nt < 8; ++nt) {
        int colc = nt * 16 + l16;
        float4_t accl[2], accn[2];
        accl[0] = accl[1] = accn[0] = accn[1] = (float4_t){0.f, 0.f, 0.f, 0.f};
        const short* bpl = lWl + colc * WPAD + quad * 8;
        const short* bpn = lWn + colc * WPAD + quad * 8;
        for (int t = 0; t < 4; ++t) {
            short8 bfl = *reinterpret_cast<const short8*>(bpl + t * 32);
            short8 bfn = *reinterpret_cast<const short8*>(bpn + t * 32);
            accl[0] = mfma_bf16(ax[0][t], bfl, accl[0]);
            accl[1] = mfma_bf16(ax[1][t], bfl, accl[1]);
            accn[0] = mfma_bf16(ax[0][t], bfn, accn[0]);
            accn[1] = mfma_bf16(ax[1][t], bfn, accn[1]);
        }
        float bLc = bl[colc];
        for (int m = 0; m < 2; ++m) {
            int row0 = rbase + m * 16 + quad * 4;
            for (int i = 0; i < 4; ++i) {
                int rr = row0 + i;
                if (rr < N) {
                    float lv = accl[m][i] + bLc;
                    out[(size_t)rr * 256 + colc] = lv > 0.f ? lv : 0.f;
                    y[(size_t)rr * D + colc] = (unsigned short)f2bf(accn[m][i]);
                }
            }
        }
    }
}

// ---------------------------------------------------------------------------
// Pull-based segment sum over bf16 y rows, fused bias+relu, writes out[:,128:].
// One wave per node; lane owns 2 cols (one dword = bf16x2). 4-edge unroll.
// ---------------------------------------------------------------------------
__global__ __launch_bounds__(256) void gather_relu_kernel(
    const unsigned short* __restrict__ y, const int* __restrict__ start,
    const int2* __restrict__ pairs, const float* __restrict__ bn,
    float* __restrict__ out, int N)
{
    int node = blockIdx.x * 4 + (threadIdx.x >> 6);
    if (node >= N) return;
    int lane = threadIdx.x & 63;
    int s = start[node];
    int e = start[node + 1];
    const unsigned* yv = reinterpret_cast<const unsigned*>(y);
    float a0 = 0.f, a1 = 0.f;
    int j = s;
    for (; j + 3 < e; j += 4) {
        int2 p0 = pairs[j], p1 = pairs[j + 1], p2 = pairs[j + 2], p3 = pairs[j + 3];
        unsigned t0 = yv[(size_t)p0.x * 64 + lane];
        unsigned t1 = yv[(size_t)p1.x * 64 + lane];
        unsigned t2 = yv[(size_t)p2.x * 64 + lane];
        unsigned t3 = yv[(size_t)p3.x * 64 + lane];
        float v0 = __int_as_float(p0.y), v1 = __int_as_float(p1.y);
        float v2 = __int_as_float(p2.y), v3 = __int_as_float(p3.y);
        a0 += v0 * bf_lo(t0); a1 += v0 * bf_hi(t0);
        a0 += v1 * bf_lo(t1); a1 += v1 * bf_hi(t1);
        a0 += v2 * bf_lo(t2); a1 += v2 * bf_hi(t2);
        a0 += v3 * bf_lo(t3); a1 += v3 * bf_hi(t3);
    }
    for (; j < e; ++j) {
        int2 p = pairs[j];
        unsigned t = yv[(size_t)p.x * 64 + lane];
        float v = __int_as_float(p.y);
        a0 += v * bf_lo(t); a1 += v * bf_hi(t);
    }
    float b0 = bn[lane * 2];
    float b1 = bn[lane * 2 + 1];
    float2 r;
    r.x = a0 + b0; r.x = r.x > 0.f ? r.x : 0.f;
    r.y = a1 + b1; r.y = r.y > 0.f ? r.y : 0.f;
    reinterpret_cast<float2*>(out + (size_t)node * 256 + D)[lane] = r;
}

extern "C" void kernel_launch(void* const* d_in, const int* in_sizes, int n_in,
                              void* d_out, int out_size, void* d_ws, size_t ws_size,
                              hipStream_t stream) {
    const float* x    = (const float*)d_in[0];
    const int*   erow = (const int*)  d_in[1];
    const int*   ecol = (const int*)  d_in[2];
    const float* eval = (const float*)d_in[3];
    const float* Wl   = (const float*)d_in[4];
    const float* bl   = (const float*)d_in[5];
    const float* Wn   = (const float*)d_in[6];
    const float* bn   = (const float*)d_in[7];
    float*       out  = (float*)d_out;

    int N = in_sizes[0] / D;
    int E = in_sizes[1];

    char* ws = (char*)d_ws;
    size_t off_y      = 0;                                        // N*D bf16
    size_t off_pairs  = off_y + (size_t)N * D * sizeof(short);
    size_t off_count  = off_pairs + (size_t)E * sizeof(int2);
    size_t off_tmp    = off_count + (size_t)N * sizeof(int);
    size_t off_start  = off_tmp + (size_t)N * sizeof(int);
    size_t off_cursor = off_start + (size_t)(N + 2) * sizeof(int);
    size_t off_bsum   = off_cursor + (size_t)N * sizeof(int);

    unsigned short* y = (unsigned short*)(ws + off_y);
    int2* pairs  = (int2*)(ws + off_pairs);
    int*  count  = (int*)(ws + off_count);
    int*  tmp    = (int*)(ws + off_tmp);
    int*  start  = (int*)(ws + off_start);
    int*  cursor = (int*)(ws + off_cursor);
    int*  bsum   = (int*)(ws + off_bsum);

    int nblocksN = (N + 255) / 256;
    int nblocksE = (E + 255) / 256;

    // CSR build (no fp32 atomics anywhere in the hot path)
    hipMemsetAsync(count, 0, (size_t)N * sizeof(int), stream);
    hist_kernel<<<nblocksE, 256, 0, stream>>>(erow, count, E);
    scan1_kernel<<<nblocksN, 256, 0, stream>>>(count, tmp, bsum, N);
    scan2_kernel<<<1, 1024, 0, stream>>>(bsum, nblocksN);
    scan3_kernel<<<nblocksN, 256, 0, stream>>>(count, tmp, bsum, start, cursor, N, E);
    reorder_kernel<<<nblocksE, 256, 0, stream>>>(erow, ecol, eval, cursor, pairs, E);

    // GEMM pass: local half of out + bf16 y = x@Wn  (runs concurrently-safe,
    // but stream-ordered after CSR; no dependency between them, order is fine)
    int gblocks = (N + 127) / 128;
    gemm_kernel<<<gblocks, 256, 0, stream>>>(x, Wl, bl, Wn, out, y, N);

    // Aggregate y by destination, add bias, relu, write neigh half of out
    gather_relu_kernel<<<(N + 3) / 4, 256, 0, stream>>>(y, start, pairs, bn, out, N);
}